// Round 2
// baseline (1062.981 us; speedup 1.0000x reference)
//
#include <hip/hip_runtime.h>
#include <hip/hip_bf16.h>
#include <stdint.h>

#define DDIM 256

typedef short s8v __attribute__((ext_vector_type(8)));
typedef float f4v __attribute__((ext_vector_type(4)));

__device__ __forceinline__ unsigned short f2bf(float f) {
    __hip_bfloat16 h = __float2bfloat16(f);
    return *reinterpret_cast<unsigned short*>(&h);
}

// ---------------- W transpose + cast: Wt[n][k] = bf16(W[k][n]) ----------------
__global__ void transpose_k(const float* __restrict__ W,
                            __hip_bfloat16* __restrict__ Wt) {
    const int n = blockIdx.x, k = threadIdx.x;
    Wt[n * DDIM + k] = __float2bfloat16(W[k * DDIM + n]);
}

// ---------------- degree counting ----------------
__global__ void count_k(const int* __restrict__ src, const int* __restrict__ dst,
                        int* __restrict__ cnt_src, int* __restrict__ cnt_dst, int E) {
    const int i = blockIdx.x * blockDim.x + threadIdx.x;
    if (i < E) {
        atomicAdd(&cnt_src[src[i]], 1);
        atomicAdd(&cnt_dst[dst[i]], 1);
    }
}

// ---------------- single-block exclusive scan (1024 threads) ----------------
__global__ void scan_k(const int* __restrict__ cnt, int* __restrict__ rowptr, int n) {
    __shared__ int wsum[16];
    __shared__ int woff[16];
    __shared__ int s_carry, s_total;
    const int t = threadIdx.x, lane = t & 63, wid = t >> 6;
    if (t == 0) s_carry = 0;
    __syncthreads();
    for (int base = 0; base < n; base += 1024) {
        const int i = base + t;
        int v = (i < n) ? cnt[i] : 0;
        int incl = v;
        #pragma unroll
        for (int off = 1; off < 64; off <<= 1) {
            int u = __shfl_up(incl, off);
            if (lane >= off) incl += u;
        }
        if (lane == 63) wsum[wid] = incl;
        __syncthreads();
        if (t < 16) {
            int x = wsum[t];
            int xs = x;
            #pragma unroll
            for (int off = 1; off < 16; off <<= 1) {
                int u = __shfl_up(xs, off, 16);
                if (t >= off) xs += u;
            }
            woff[t] = xs - x;
            if (t == 15) s_total = xs;
        }
        __syncthreads();
        const int carry = s_carry;
        if (i < n) rowptr[i] = carry + woff[wid] + (incl - v);
        __syncthreads();
        if (t == 0) s_carry = carry + s_total;
        __syncthreads();
    }
    if (t == 0) rowptr[n] = s_carry;
}

// ---------------- CSR fill (stores src index + rsqrt(deg_out(src))) ----------------
__global__ void fill_k(const int* __restrict__ src, const int* __restrict__ dst,
                       const int* __restrict__ cnt_src, const int* __restrict__ rowptr,
                       int* __restrict__ cursor, int2* __restrict__ sorted, int E) {
    const int i = blockIdx.x * blockDim.x + threadIdx.x;
    if (i < E) {
        const int s = src[i], d = dst[i];
        const int pos = atomicAdd(&cursor[d], 1);
        const int cs = cnt_src[s];
        const float c = rsqrtf((float)(cs < 1 ? 1 : cs));
        int2 rec;
        rec.x = s;
        rec.y = __float_as_int(c);
        sorted[rowptr[d] + pos] = rec;
    }
}

// ---------------- gather: 1 wave per dst row, f32 exact ----------------
__global__ __launch_bounds__(256) void gather_k(
    const int2* __restrict__ sorted, const int* __restrict__ rowptr,
    const int* __restrict__ cnt_dst, const float* __restrict__ X,
    float* __restrict__ agg, int n_dst) {
    const int lane = threadIdx.x & 63, wid = threadIdx.x >> 6;
    const int row = blockIdx.x * 4 + wid;
    if (row >= n_dst) return;
    const int beg = rowptr[row], end = rowptr[row + 1];
    f4v a = (f4v){0.f, 0.f, 0.f, 0.f};
    for (int j = beg; j < end; ++j) {
        const int2 rec = sorted[j];
        const float c = __int_as_float(rec.y);
        const f4v v = reinterpret_cast<const f4v*>(X + (size_t)rec.x * DDIM)[lane];
        a += c * v;
    }
    const int cd = cnt_dst[row];
    const float s = rsqrtf((float)(cd < 1 ? 1 : cd));
    reinterpret_cast<f4v*>(agg + (size_t)row * DDIM)[lane] = a * s;
}

// ---------------- fused GEMM (MFMA bf16, K=256 or 512) + LayerNorm + bias + ReLU ----------------
// out[r][:] = relu( LN(A0@W0 (+ A1@W1))[r] * gamma + beta + bias )   all f32 I/O
// Block: 256 thr = 4 waves; wave owns 16 complete rows (full N=256). No LDS.
__global__ __launch_bounds__(256) void gemm_ln_k(
    const float* __restrict__ A0, const __hip_bfloat16* __restrict__ Wt0,
    const float* __restrict__ A1, const __hip_bfloat16* __restrict__ Wt1,
    const float* __restrict__ gamma, const float* __restrict__ beta,
    const float* __restrict__ bias, float* __restrict__ out, int M) {
    const int lane = threadIdx.x & 63, wid = threadIdx.x >> 6;
    const int r0 = blockIdx.x * 64 + wid * 16;
    if (r0 >= M) return;
    const int c = lane & 15;   // col-in-tile (C/D), row-in-A-frag, col-in-B-frag
    const int kb = lane >> 4;  // k-block (input frags), row-group (C/D)

    f4v acc[16];
    #pragma unroll
    for (int nt = 0; nt < 16; ++nt) acc[nt] = (f4v){0.f, 0.f, 0.f, 0.f};

    const int npass = (A1 != nullptr) ? 2 : 1;
    for (int p = 0; p < npass; ++p) {
        const float* A = (p == 0) ? A0 : A1;
        const __hip_bfloat16* Wt = (p == 0) ? Wt0 : Wt1;
        for (int ks = 0; ks < 8; ++ks) {
            const int k0 = ks * 32 + kb * 8;
            const f4v x0 = reinterpret_cast<const f4v*>(A + (size_t)(r0 + c) * DDIM + k0)[0];
            const f4v x1 = reinterpret_cast<const f4v*>(A + (size_t)(r0 + c) * DDIM + k0)[1];
            union { s8v v; unsigned short u[8]; } af;
            #pragma unroll
            for (int j = 0; j < 4; ++j) {
                af.u[j]     = f2bf(x0[j]);
                af.u[4 + j] = f2bf(x1[j]);
            }
            #pragma unroll
            for (int nt = 0; nt < 16; ++nt) {
                const s8v bfr = *reinterpret_cast<const s8v*>(Wt + (size_t)(nt * 16 + c) * DDIM + k0);
                acc[nt] = __builtin_amdgcn_mfma_f32_16x16x32_bf16(af.v, bfr, acc[nt], 0, 0, 0);
            }
        }
    }

    // LayerNorm: wave-local. lane holds rows {kb*4+j}, cols {nt*16+c}.
    float s[4] = {0.f, 0.f, 0.f, 0.f}, q[4] = {0.f, 0.f, 0.f, 0.f};
    #pragma unroll
    for (int nt = 0; nt < 16; ++nt)
        #pragma unroll
        for (int j = 0; j < 4; ++j) {
            const float v = acc[nt][j];
            s[j] += v;
            q[j] += v * v;
        }
    #pragma unroll
    for (int off = 1; off < 16; off <<= 1) {
        #pragma unroll
        for (int j = 0; j < 4; ++j) {
            s[j] += __shfl_xor(s[j], off);
            q[j] += __shfl_xor(q[j], off);
        }
    }
    float mu[4], rs[4];
    #pragma unroll
    for (int j = 0; j < 4; ++j) {
        mu[j] = s[j] * (1.f / 256.f);
        float var = q[j] * (1.f / 256.f) - mu[j] * mu[j];
        var = fmaxf(var, 0.f);
        rs[j] = rsqrtf(var + 1e-5f);
    }
    #pragma unroll
    for (int nt = 0; nt < 16; ++nt) {
        const int col = nt * 16 + c;
        const float g  = gamma[col];
        const float be = beta[col];
        const float bb = bias[col];
        #pragma unroll
        for (int j = 0; j < 4; ++j) {
            float v = (acc[nt][j] - mu[j]) * rs[j] * g + be + bb;
            v = fmaxf(v, 0.f);
            out[(size_t)(r0 + kb * 4 + j) * DDIM + col] = v;
        }
    }
}

extern "C" void kernel_launch(void* const* d_in, const int* in_sizes, int n_in,
                              void* d_out, int out_size, void* d_ws, size_t ws_size,
                              hipStream_t stream) {
    const float* x_cell     = (const float*)d_in[0];
    const float* x_gene     = (const float*)d_in[1];
    const float* W_cg       = (const float*)d_in[2];
    const float* W_gc       = (const float*)d_in[3];
    const float* W_gg       = (const float*)d_in[4];
    const float* gamma_cell = (const float*)d_in[5];
    const float* beta_cell  = (const float*)d_in[6];
    const float* gamma_gene = (const float*)d_in[7];
    const float* beta_gene  = (const float*)d_in[8];
    const float* b_cell     = (const float*)d_in[9];
    const float* b_gene     = (const float*)d_in[10];
    const int* src_cg = (const int*)d_in[11];
    const int* dst_cg = (const int*)d_in[12];
    const int* src_gc = (const int*)d_in[13];
    const int* dst_gc = (const int*)d_in[14];
    const int* src_gg = (const int*)d_in[15];
    const int* dst_gg = (const int*)d_in[16];

    const int N = in_sizes[0] / DDIM;   // 50000
    const int E = in_sizes[11];         // 800000

    // workspace layout (~7.6 MB)
    char* wsb = (char*)d_ws;
    int2* sorted   = (int2*)(wsb);                  // E*8 = 6,400,000 B
    int*  cnt_src  = (int*)(wsb + 6400000);         // 200,000 B
    int*  cnt_dst  = (int*)(wsb + 6600000);         // 200,000 B
    int*  cursor   = (int*)(wsb + 6800000);         // 200,000 B
    int*  rowptr   = (int*)(wsb + 7000000);         // 200,004 B
    __hip_bfloat16* Wt_cg = (__hip_bfloat16*)(wsb + 7200256);  // 131,072 B each
    __hip_bfloat16* Wt_gc = (__hip_bfloat16*)(wsb + 7331328);
    __hip_bfloat16* Wt_gg = (__hip_bfloat16*)(wsb + 7462400);

    float* out0 = (float*)d_out;                // cell half (also agg scratch, f32)
    float* out1 = out0 + (size_t)N * DDIM;      // gene half (also agg scratch, f32)

    transpose_k<<<DDIM, DDIM, 0, stream>>>(W_cg, Wt_cg);
    transpose_k<<<DDIM, DDIM, 0, stream>>>(W_gc, Wt_gc);
    transpose_k<<<DDIM, DDIM, 0, stream>>>(W_gg, Wt_gg);

    const int cntBlocks = (E + 255) / 256;
    const int gatherBlocks = (N + 3) / 4;
    const int gemmBlocks = (N + 63) / 64;

    // relation cg (cell -> gene): agg -> out0 region
    hipMemsetAsync(cnt_src, 0, 600000, stream);
    count_k<<<cntBlocks, 256, 0, stream>>>(src_cg, dst_cg, cnt_src, cnt_dst, E);
    scan_k<<<1, 1024, 0, stream>>>(cnt_dst, rowptr, N);
    fill_k<<<cntBlocks, 256, 0, stream>>>(src_cg, dst_cg, cnt_src, rowptr, cursor, sorted, E);
    gather_k<<<gatherBlocks, 256, 0, stream>>>(sorted, rowptr, cnt_dst, x_cell, out0, N);

    // relation gg (gene -> gene): agg -> out1 region
    hipMemsetAsync(cnt_src, 0, 600000, stream);
    count_k<<<cntBlocks, 256, 0, stream>>>(src_gg, dst_gg, cnt_src, cnt_dst, E);
    scan_k<<<1, 1024, 0, stream>>>(cnt_dst, rowptr, N);
    fill_k<<<cntBlocks, 256, 0, stream>>>(src_gg, dst_gg, cnt_src, rowptr, cursor, sorted, E);
    gather_k<<<gatherBlocks, 256, 0, stream>>>(sorted, rowptr, cnt_dst, x_gene, out1, N);

    // h_gene = agg_cg@W_cg + agg_gg@W_gg, fused LN -> out1 (final gene output)
    gemm_ln_k<<<gemmBlocks, 256, 0, stream>>>(out0, Wt_cg, out1, Wt_gg,
                                              gamma_gene, beta_gene, b_gene, out1, N);

    // relation gc (gene -> cell): agg -> out0 region (agg_cg already consumed)
    hipMemsetAsync(cnt_src, 0, 600000, stream);
    count_k<<<cntBlocks, 256, 0, stream>>>(src_gc, dst_gc, cnt_src, cnt_dst, E);
    scan_k<<<1, 1024, 0, stream>>>(cnt_dst, rowptr, N);
    fill_k<<<cntBlocks, 256, 0, stream>>>(src_gc, dst_gc, cnt_src, rowptr, cursor, sorted, E);
    gather_k<<<gatherBlocks, 256, 0, stream>>>(sorted, rowptr, cnt_dst, x_gene, out0, N);

    // h_cell = agg_gc@W_gc, fused LN -> out0 (final cell output)
    gemm_ln_k<<<gemmBlocks, 256, 0, stream>>>(out0, Wt_gc, nullptr, nullptr,
                                              gamma_cell, beta_cell, b_cell, out0, N);
}

// Round 3
// 766.207 us; speedup vs baseline: 1.3873x; 1.3873x over previous
//
#include <hip/hip_runtime.h>
#include <hip/hip_bf16.h>
#include <stdint.h>

#define DDIM 256

typedef short s8v __attribute__((ext_vector_type(8)));
typedef float f4v __attribute__((ext_vector_type(4)));

__device__ __forceinline__ float bf2f(unsigned u) { return __uint_as_float(u << 16); }
__device__ __forceinline__ unsigned short f2bf(float f) {
    __hip_bfloat16 h = __float2bfloat16(f);
    return *reinterpret_cast<unsigned short*>(&h);
}
__device__ __forceinline__ unsigned pack2(float a, float b) {
    return (unsigned)f2bf(a) | ((unsigned)f2bf(b) << 16);
}

// ---------------- W transpose + cast: Wt[n][k] = bf16(W[k][n]) ----------------
__global__ void transpose_k(const float* __restrict__ W,
                            __hip_bfloat16* __restrict__ Wt) {
    const int n = blockIdx.x, k = threadIdx.x;
    Wt[n * DDIM + k] = __float2bfloat16(W[k * DDIM + n]);
}

// ---------------- degree counting ----------------
__global__ void count_k(const int* __restrict__ src, const int* __restrict__ dst,
                        int* __restrict__ cnt_src, int* __restrict__ cnt_dst, int E) {
    const int i = blockIdx.x * blockDim.x + threadIdx.x;
    if (i < E) {
        atomicAdd(&cnt_src[src[i]], 1);
        atomicAdd(&cnt_dst[dst[i]], 1);
    }
}

// ---------------- segment allocator (replaces prefix scan; order irrelevant) ----------------
__global__ void alloc_k(const int* __restrict__ cnt, int* __restrict__ start,
                        int* __restrict__ total, int n) {
    const int i = blockIdx.x * blockDim.x + threadIdx.x;
    const int lane = threadIdx.x & 63;
    int v = (i < n) ? cnt[i] : 0;
    int incl = v;
    #pragma unroll
    for (int off = 1; off < 64; off <<= 1) {
        int u = __shfl_up(incl, off);
        if (lane >= off) incl += u;
    }
    int base = 0;
    if (lane == 63) base = atomicAdd(total, incl);
    base = __shfl(base, 63);
    if (i < n) start[i] = base + incl - v;
}

// ---------------- CSR fill (stores src index + rsqrt(deg_out(src))) ----------------
__global__ void fill_k(const int* __restrict__ src, const int* __restrict__ dst,
                       const int* __restrict__ cnt_src, const int* __restrict__ start,
                       int* __restrict__ cursor, int2* __restrict__ sorted, int E) {
    const int i = blockIdx.x * blockDim.x + threadIdx.x;
    if (i < E) {
        const int s = src[i], d = dst[i];
        const int pos = atomicAdd(&cursor[d], 1);
        const int cs = cnt_src[s];
        const float c = rsqrtf((float)(cs < 1 ? 1 : cs));
        int2 rec;
        rec.x = s;
        rec.y = __float_as_int(c);
        sorted[start[d] + pos] = rec;
    }
}

// ---------------- dense GEMM: Y = bf16( X[M,256] @ W[256,256] ) ----------------
// Swapped MFMA operands (A-op = Wt fragment, B-op = X fragment) so each lane owns
// one Y row and 4 consecutive cols per tile -> packed 8B stores.
// All 16 X-loads pre-issued per wave (256 B/lane in flight) to ride HBM latency.
__global__ __launch_bounds__(256) void gemm_k(
    const float* __restrict__ X, const __hip_bfloat16* __restrict__ Wt,
    __hip_bfloat16* __restrict__ Y, int M) {
    const int lane = threadIdx.x & 63, wid = threadIdx.x >> 6;
    const int r0 = blockIdx.x * 64 + wid * 16;
    if (r0 >= M) return;
    const int c = lane & 15;   // Y row offset (B-frag col); Wt row offset (A-frag row)
    const int kb = lane >> 4;  // k-slice selector

    const float* xrow = X + (size_t)(r0 + c) * DDIM;
    f4v xq[16];
    #pragma unroll
    for (int ks = 0; ks < 8; ++ks) {
        xq[2 * ks]     = reinterpret_cast<const f4v*>(xrow + ks * 32 + kb * 8)[0];
        xq[2 * ks + 1] = reinterpret_cast<const f4v*>(xrow + ks * 32 + kb * 8)[1];
    }

    f4v acc[16];
    #pragma unroll
    for (int nt = 0; nt < 16; ++nt) acc[nt] = (f4v){0.f, 0.f, 0.f, 0.f};

    #pragma unroll
    for (int ks = 0; ks < 8; ++ks) {
        union { s8v v; unsigned short u[8]; } xf;
        #pragma unroll
        for (int j = 0; j < 4; ++j) {
            xf.u[j]     = f2bf(xq[2 * ks][j]);
            xf.u[4 + j] = f2bf(xq[2 * ks + 1][j]);
        }
        const int k0 = ks * 32 + kb * 8;
        #pragma unroll
        for (int nt = 0; nt < 16; ++nt) {
            const s8v wf = *reinterpret_cast<const s8v*>(Wt + (size_t)(nt * 16 + c) * DDIM + k0);
            acc[nt] = __builtin_amdgcn_mfma_f32_16x16x32_bf16(wf, xf.v, acc[nt], 0, 0, 0);
        }
    }

    // lane holds Y[r0+c][nt*16 + kb*4 + j], j=0..3 -> pack 4 bf16 = uint2
    __hip_bfloat16* yrow = Y + (size_t)(r0 + c) * DDIM;
    #pragma unroll
    for (int nt = 0; nt < 16; ++nt) {
        uint2 o;
        o.x = pack2(acc[nt][0], acc[nt][1]);
        o.y = pack2(acc[nt][2], acc[nt][3]);
        *reinterpret_cast<uint2*>(yrow + nt * 16 + kb * 4) = o;
    }
}

// ---------------- gather helpers ----------------
__device__ __forceinline__ void acc4(f4v& a, float c, uint2 v) {
    a[0] += c * bf2f(v.x & 0xffffu);
    a[1] += c * bf2f(v.x >> 16);
    a[2] += c * bf2f(v.y & 0xffffu);
    a[3] += c * bf2f(v.y >> 16);
}

__device__ __forceinline__ f4v seg_sum(const int2* __restrict__ sorted, int b, int n,
                                       const __hip_bfloat16* __restrict__ Y, int lane) {
    f4v a = (f4v){0.f, 0.f, 0.f, 0.f};
    int j = 0;
    for (; j + 4 <= n; j += 4) {
        const int2 e0 = sorted[b + j + 0];
        const int2 e1 = sorted[b + j + 1];
        const int2 e2 = sorted[b + j + 2];
        const int2 e3 = sorted[b + j + 3];
        const uint2 v0 = reinterpret_cast<const uint2*>(Y + (size_t)e0.x * DDIM)[lane];
        const uint2 v1 = reinterpret_cast<const uint2*>(Y + (size_t)e1.x * DDIM)[lane];
        const uint2 v2 = reinterpret_cast<const uint2*>(Y + (size_t)e2.x * DDIM)[lane];
        const uint2 v3 = reinterpret_cast<const uint2*>(Y + (size_t)e3.x * DDIM)[lane];
        acc4(a, __int_as_float(e0.y), v0);
        acc4(a, __int_as_float(e1.y), v1);
        acc4(a, __int_as_float(e2.y), v2);
        acc4(a, __int_as_float(e3.y), v3);
    }
    for (; j < n; ++j) {
        const int2 e = sorted[b + j];
        const uint2 v = reinterpret_cast<const uint2*>(Y + (size_t)e.x * DDIM)[lane];
        acc4(a, __int_as_float(e.y), v);
    }
    return a;
}

// ---------------- gene pass 1: scaled partial (f32) into out-gene region ----------------
__global__ __launch_bounds__(256) void gather_part_k(
    const int2* __restrict__ sorted, const int* __restrict__ start,
    const int* __restrict__ cnt_dst, const __hip_bfloat16* __restrict__ Y,
    float* __restrict__ partial, int n_dst) {
    const int lane = threadIdx.x & 63, wid = threadIdx.x >> 6;
    const int row = blockIdx.x * 4 + wid;
    if (row >= n_dst) return;
    const int n = cnt_dst[row];
    f4v a = seg_sum(sorted, start[row], n, Y, lane);
    const float s = rsqrtf((float)(n < 1 ? 1 : n));
    reinterpret_cast<f4v*>(partial + (size_t)row * DDIM)[lane] = a * s;
}

// ---------------- gather + (optional partial add) + LayerNorm + bias + ReLU ----------------
__global__ __launch_bounds__(256) void gather_ln_k(
    const int2* __restrict__ sorted, const int* __restrict__ start,
    const int* __restrict__ cnt_dst, const __hip_bfloat16* __restrict__ Y,
    const float* __restrict__ partial,  // may be null
    const float* __restrict__ gamma, const float* __restrict__ beta,
    const float* __restrict__ bias, float* __restrict__ out, int n_dst) {
    const int lane = threadIdx.x & 63, wid = threadIdx.x >> 6;
    const int row = blockIdx.x * 4 + wid;
    if (row >= n_dst) return;
    const int n = cnt_dst[row];
    f4v a = seg_sum(sorted, start[row], n, Y, lane);
    const float s = rsqrtf((float)(n < 1 ? 1 : n));
    a *= s;
    if (partial != nullptr)
        a += reinterpret_cast<const f4v*>(partial + (size_t)row * DDIM)[lane];

    // LayerNorm across the row (64 lanes x 4 vals)
    float s1 = a[0] + a[1] + a[2] + a[3];
    float s2 = a[0] * a[0] + a[1] * a[1] + a[2] * a[2] + a[3] * a[3];
    #pragma unroll
    for (int off = 1; off < 64; off <<= 1) {
        s1 += __shfl_xor(s1, off);
        s2 += __shfl_xor(s2, off);
    }
    const float mu = s1 * (1.f / 256.f);
    float var = s2 * (1.f / 256.f) - mu * mu;
    var = fmaxf(var, 0.f);
    const float rs = rsqrtf(var + 1e-5f);

    const f4v g  = reinterpret_cast<const f4v*>(gamma)[lane];
    const f4v be = reinterpret_cast<const f4v*>(beta)[lane];
    const f4v bb = reinterpret_cast<const f4v*>(bias)[lane];
    f4v o;
    #pragma unroll
    for (int j = 0; j < 4; ++j) {
        float v = (a[j] - mu) * rs * g[j] + be[j] + bb[j];
        o[j] = fmaxf(v, 0.f);
    }
    reinterpret_cast<f4v*>(out + (size_t)row * DDIM)[lane] = o;
}

extern "C" void kernel_launch(void* const* d_in, const int* in_sizes, int n_in,
                              void* d_out, int out_size, void* d_ws, size_t ws_size,
                              hipStream_t stream) {
    const float* x_cell     = (const float*)d_in[0];
    const float* x_gene     = (const float*)d_in[1];
    const float* W_cg       = (const float*)d_in[2];
    const float* W_gc       = (const float*)d_in[3];
    const float* W_gg       = (const float*)d_in[4];
    const float* gamma_cell = (const float*)d_in[5];
    const float* beta_cell  = (const float*)d_in[6];
    const float* gamma_gene = (const float*)d_in[7];
    const float* beta_gene  = (const float*)d_in[8];
    const float* b_cell     = (const float*)d_in[9];
    const float* b_gene     = (const float*)d_in[10];
    const int* src_cg = (const int*)d_in[11];
    const int* dst_cg = (const int*)d_in[12];
    const int* src_gc = (const int*)d_in[13];
    const int* dst_gc = (const int*)d_in[14];
    const int* src_gg = (const int*)d_in[15];
    const int* dst_gg = (const int*)d_in[16];

    const int N = in_sizes[0] / DDIM;   // 50000
    const int E = in_sizes[11];         // 800000

    // workspace layout (~33.2 MB)
    char* wsb = (char*)d_ws;
    int2* sorted  = (int2*)(wsb);                   // E*8 = 6,400,000
    int*  cnt_src = (int*)(wsb + 6400000);          // 200,000
    int*  cnt_dst = (int*)(wsb + 6600000);          // 200,000
    int*  cursor  = (int*)(wsb + 6800000);          // 200,000
    int*  total   = (int*)(wsb + 7000000);          // 256 (pad)
    int*  start   = (int*)(wsb + 7000256);          // 200,000
    __hip_bfloat16* Wt_cg = (__hip_bfloat16*)(wsb + 7200256);   // 131,072 each
    __hip_bfloat16* Wt_gc = (__hip_bfloat16*)(wsb + 7331328);
    __hip_bfloat16* Wt_gg = (__hip_bfloat16*)(wsb + 7462400);
    __hip_bfloat16* Ybuf  = (__hip_bfloat16*)(wsb + 7593472);   // 25,600,000

    float* out_cell = (float*)d_out;
    float* out_gene = out_cell + (size_t)N * DDIM;

    const int cntBlocks    = (E + 255) / 256;
    const int allocBlocks  = (N + 255) / 256;
    const int gatherBlocks = (N + 3) / 4;
    const int gemmBlocks   = (N + 63) / 64;

    transpose_k<<<DDIM, DDIM, 0, stream>>>(W_cg, Wt_cg);
    transpose_k<<<DDIM, DDIM, 0, stream>>>(W_gc, Wt_gc);
    transpose_k<<<DDIM, DDIM, 0, stream>>>(W_gg, Wt_gg);

    // ---- relation gc (gene -> cell): out_cell ----
    hipMemsetAsync(cnt_src, 0, 600256, stream);
    count_k<<<cntBlocks, 256, 0, stream>>>(src_gc, dst_gc, cnt_src, cnt_dst, E);
    alloc_k<<<allocBlocks, 256, 0, stream>>>(cnt_dst, start, total, N);
    fill_k<<<cntBlocks, 256, 0, stream>>>(src_gc, dst_gc, cnt_src, start, cursor, sorted, E);
    gemm_k<<<gemmBlocks, 256, 0, stream>>>(x_gene, Wt_gc, Ybuf, N);
    gather_ln_k<<<gatherBlocks, 256, 0, stream>>>(sorted, start, cnt_dst, Ybuf, nullptr,
                                                  gamma_cell, beta_cell, b_cell, out_cell, N);

    // ---- relation cg (cell -> gene): partial into out_gene ----
    hipMemsetAsync(cnt_src, 0, 600256, stream);
    count_k<<<cntBlocks, 256, 0, stream>>>(src_cg, dst_cg, cnt_src, cnt_dst, E);
    alloc_k<<<allocBlocks, 256, 0, stream>>>(cnt_dst, start, total, N);
    fill_k<<<cntBlocks, 256, 0, stream>>>(src_cg, dst_cg, cnt_src, start, cursor, sorted, E);
    gemm_k<<<gemmBlocks, 256, 0, stream>>>(x_cell, Wt_cg, Ybuf, N);
    gather_part_k<<<gatherBlocks, 256, 0, stream>>>(sorted, start, cnt_dst, Ybuf, out_gene, N);

    // ---- relation gg (gene -> gene): add partial, LN -> out_gene ----
    hipMemsetAsync(cnt_src, 0, 600256, stream);
    count_k<<<cntBlocks, 256, 0, stream>>>(src_gg, dst_gg, cnt_src, cnt_dst, E);
    alloc_k<<<allocBlocks, 256, 0, stream>>>(cnt_dst, start, total, N);
    fill_k<<<cntBlocks, 256, 0, stream>>>(src_gg, dst_gg, cnt_src, start, cursor, sorted, E);
    gemm_k<<<gemmBlocks, 256, 0, stream>>>(x_gene, Wt_gg, Ybuf, N);
    gather_ln_k<<<gatherBlocks, 256, 0, stream>>>(sorted, start, cnt_dst, Ybuf, out_gene,
                                                  gamma_gene, beta_gene, b_gene, out_gene, N);
}

// Round 4
// 709.737 us; speedup vs baseline: 1.4977x; 1.0796x over previous
//
#include <hip/hip_runtime.h>
#include <hip/hip_bf16.h>
#include <stdint.h>

#define DDIM 256

typedef short s8v __attribute__((ext_vector_type(8)));
typedef float f4v __attribute__((ext_vector_type(4)));

__device__ __forceinline__ float bf2f(unsigned u) { return __uint_as_float(u << 16); }
__device__ __forceinline__ unsigned short f2bf(float f) {
    __hip_bfloat16 h = __float2bfloat16(f);
    return *reinterpret_cast<unsigned short*>(&h);
}
__device__ __forceinline__ unsigned pack2(float a, float b) {
    return (unsigned)f2bf(a) | ((unsigned)f2bf(b) << 16);
}

// ---------------- fused W transpose + cast: T[n][k] = bf16(W[k][n]) ----------------
__global__ void transpose3_k(const float* __restrict__ W0, const float* __restrict__ W1,
                             const float* __restrict__ W2, __hip_bfloat16* __restrict__ T0,
                             __hip_bfloat16* __restrict__ T1, __hip_bfloat16* __restrict__ T2) {
    const float* W = (blockIdx.y == 0) ? W0 : (blockIdx.y == 1) ? W1 : W2;
    __hip_bfloat16* T = (blockIdx.y == 0) ? T0 : (blockIdx.y == 1) ? T1 : T2;
    T[blockIdx.x * DDIM + threadIdx.x] = __float2bfloat16(W[threadIdx.x * DDIM + blockIdx.x]);
}

// ---------------- degree counting, all 3 relations ----------------
// cb layout: [cs0][cd0][cs1][cd1][cs2][cd2], each n ints
__global__ void count_all_k(const int* __restrict__ s0, const int* __restrict__ d0,
                            const int* __restrict__ s1, const int* __restrict__ d1,
                            const int* __restrict__ s2, const int* __restrict__ d2,
                            int* __restrict__ cb, int n, int E) {
    const int i = blockIdx.x * blockDim.x + threadIdx.x;
    if (i >= E) return;
    atomicAdd(cb + s0[i], 1);
    atomicAdd(cb + n + d0[i], 1);
    atomicAdd(cb + 2 * n + s1[i], 1);
    atomicAdd(cb + 3 * n + d1[i], 1);
    atomicAdd(cb + 4 * n + s2[i], 1);
    atomicAdd(cb + 5 * n + d2[i], 1);
}

// ---------------- segment allocator (order irrelevant), 3 relations ----------------
__global__ void alloc3_k(const int* __restrict__ cb, int* __restrict__ starts,
                         int* __restrict__ totals, int n, int nb) {
    const int r = blockIdx.x / nb;
    const int i = (blockIdx.x % nb) * blockDim.x + threadIdx.x;
    const int lane = threadIdx.x & 63;
    const int* cnt = cb + (2 * r + 1) * n;   // cd_r
    int v = (i < n) ? cnt[i] : 0;
    int incl = v;
    #pragma unroll
    for (int off = 1; off < 64; off <<= 1) {
        int u = __shfl_up(incl, off);
        if (lane >= off) incl += u;
    }
    int base = 0;
    if (lane == 63) base = atomicAdd(&totals[r], incl);
    base = __shfl(base, 63);
    if (i < n) starts[r * n + i] = base + incl - v;
}

// ---------------- CSR fill, 3 relations; starts[] doubles as cursor ----------------
__global__ void fill_all_k(const int* __restrict__ s0, const int* __restrict__ d0,
                           const int* __restrict__ s1, const int* __restrict__ d1,
                           const int* __restrict__ s2, const int* __restrict__ d2,
                           int* __restrict__ starts, int* __restrict__ srt0,
                           int* __restrict__ srt1, int* __restrict__ srt2, int n, int E) {
    const int i = blockIdx.x * blockDim.x + threadIdx.x;
    if (i >= E) return;
    { const int pos = atomicAdd(&starts[d0[i]], 1);         srt0[pos] = s0[i]; }
    { const int pos = atomicAdd(&starts[n + d1[i]], 1);     srt1[pos] = s1[i]; }
    { const int pos = atomicAdd(&starts[2 * n + d2[i]], 1); srt2[pos] = s2[i]; }
}

// ---------------- dual-output GEMM: Y0 = bf16(s0(X@W0)), Y1 = bf16(s1(X@W1)) ----------------
// 32 rows/wave (two 16-row B-fragments) -> each Wt fragment load feeds 2 MFMAs/relation.
// Row scale = rsqrt(deg_out) folded into epilogue.
__global__ __launch_bounds__(256) void gemm2_k(
    const float* __restrict__ X,
    const __hip_bfloat16* __restrict__ Wt0, const __hip_bfloat16* __restrict__ Wt1,
    const int* __restrict__ deg0, const int* __restrict__ deg1,
    __hip_bfloat16* __restrict__ Y0, __hip_bfloat16* __restrict__ Y1, int M) {
    const int lane = threadIdx.x & 63, wid = threadIdx.x >> 6;
    const int c = lane & 15, kb = lane >> 4;
    const int rA = blockIdx.x * 128 + wid * 32 + c;   // rows rA, rA+16
    const int rB = rA + 16;
    const bool vA = rA < M, vB = rB < M;
    const int rAc = vA ? rA : (M - 1), rBc = vB ? rB : (M - 1);

    // load + convert both X rows (f32 -> bf16 fragments)
    s8v xfA[8], xfB[8];
    const float* xA = X + (size_t)rAc * DDIM;
    const float* xB = X + (size_t)rBc * DDIM;
    #pragma unroll
    for (int ks = 0; ks < 8; ++ks) {
        const int k0 = ks * 32 + kb * 8;
        const f4v a0 = *reinterpret_cast<const f4v*>(xA + k0);
        const f4v a1 = *reinterpret_cast<const f4v*>(xA + k0 + 4);
        const f4v b0 = *reinterpret_cast<const f4v*>(xB + k0);
        const f4v b1 = *reinterpret_cast<const f4v*>(xB + k0 + 4);
        union { s8v v; unsigned short u[8]; } fa, fb;
        #pragma unroll
        for (int j = 0; j < 4; ++j) {
            fa.u[j] = f2bf(a0[j]); fa.u[4 + j] = f2bf(a1[j]);
            fb.u[j] = f2bf(b0[j]); fb.u[4 + j] = f2bf(b1[j]);
        }
        xfA[ks] = fa.v; xfB[ks] = fb.v;
    }

    const int dA0 = deg0[rAc], dB0 = deg0[rBc], dA1 = deg1[rAc], dB1 = deg1[rBc];
    const float s0A = rsqrtf((float)(dA0 < 1 ? 1 : dA0));
    const float s0B = rsqrtf((float)(dB0 < 1 ? 1 : dB0));
    const float s1A = rsqrtf((float)(dA1 < 1 ? 1 : dA1));
    const float s1B = rsqrtf((float)(dB1 < 1 ? 1 : dB1));

    #pragma unroll 2
    for (int nt = 0; nt < 16; ++nt) {
        const __hip_bfloat16* w0p = Wt0 + (size_t)(nt * 16 + c) * DDIM + kb * 8;
        const __hip_bfloat16* w1p = Wt1 + (size_t)(nt * 16 + c) * DDIM + kb * 8;
        s8v wf0[8], wf1[8];
        #pragma unroll
        for (int ks = 0; ks < 8; ++ks) {
            wf0[ks] = *reinterpret_cast<const s8v*>(w0p + ks * 32);
            wf1[ks] = *reinterpret_cast<const s8v*>(w1p + ks * 32);
        }
        f4v a00 = (f4v){0.f,0.f,0.f,0.f}, a01 = a00, a10 = a00, a11 = a00;
        #pragma unroll
        for (int ks = 0; ks < 8; ++ks) {
            a00 = __builtin_amdgcn_mfma_f32_16x16x32_bf16(wf0[ks], xfA[ks], a00, 0, 0, 0);
            a10 = __builtin_amdgcn_mfma_f32_16x16x32_bf16(wf0[ks], xfB[ks], a10, 0, 0, 0);
            a01 = __builtin_amdgcn_mfma_f32_16x16x32_bf16(wf1[ks], xfA[ks], a01, 0, 0, 0);
            a11 = __builtin_amdgcn_mfma_f32_16x16x32_bf16(wf1[ks], xfB[ks], a11, 0, 0, 0);
        }
        const int col = nt * 16 + kb * 4;
        if (vA) {
            uint2 o0, o1;
            o0.x = pack2(a00[0] * s0A, a00[1] * s0A); o0.y = pack2(a00[2] * s0A, a00[3] * s0A);
            o1.x = pack2(a01[0] * s1A, a01[1] * s1A); o1.y = pack2(a01[2] * s1A, a01[3] * s1A);
            *reinterpret_cast<uint2*>(Y0 + (size_t)rA * DDIM + col) = o0;
            *reinterpret_cast<uint2*>(Y1 + (size_t)rA * DDIM + col) = o1;
        }
        if (vB) {
            uint2 o0, o1;
            o0.x = pack2(a10[0] * s0B, a10[1] * s0B); o0.y = pack2(a10[2] * s0B, a10[3] * s0B);
            o1.x = pack2(a11[0] * s1B, a11[1] * s1B); o1.y = pack2(a11[2] * s1B, a11[3] * s1B);
            *reinterpret_cast<uint2*>(Y0 + (size_t)rB * DDIM + col) = o0;
            *reinterpret_cast<uint2*>(Y1 + (size_t)rB * DDIM + col) = o1;
        }
    }
}

// ---------------- single-output GEMM (same structure) ----------------
__global__ __launch_bounds__(256) void gemm1_k(
    const float* __restrict__ X, const __hip_bfloat16* __restrict__ Wt0,
    const int* __restrict__ deg0, __hip_bfloat16* __restrict__ Y0, int M) {
    const int lane = threadIdx.x & 63, wid = threadIdx.x >> 6;
    const int c = lane & 15, kb = lane >> 4;
    const int rA = blockIdx.x * 128 + wid * 32 + c;
    const int rB = rA + 16;
    const bool vA = rA < M, vB = rB < M;
    const int rAc = vA ? rA : (M - 1), rBc = vB ? rB : (M - 1);

    s8v xfA[8], xfB[8];
    const float* xA = X + (size_t)rAc * DDIM;
    const float* xB = X + (size_t)rBc * DDIM;
    #pragma unroll
    for (int ks = 0; ks < 8; ++ks) {
        const int k0 = ks * 32 + kb * 8;
        const f4v a0 = *reinterpret_cast<const f4v*>(xA + k0);
        const f4v a1 = *reinterpret_cast<const f4v*>(xA + k0 + 4);
        const f4v b0 = *reinterpret_cast<const f4v*>(xB + k0);
        const f4v b1 = *reinterpret_cast<const f4v*>(xB + k0 + 4);
        union { s8v v; unsigned short u[8]; } fa, fb;
        #pragma unroll
        for (int j = 0; j < 4; ++j) {
            fa.u[j] = f2bf(a0[j]); fa.u[4 + j] = f2bf(a1[j]);
            fb.u[j] = f2bf(b0[j]); fb.u[4 + j] = f2bf(b1[j]);
        }
        xfA[ks] = fa.v; xfB[ks] = fb.v;
    }
    const int dA0 = deg0[rAc], dB0 = deg0[rBc];
    const float s0A = rsqrtf((float)(dA0 < 1 ? 1 : dA0));
    const float s0B = rsqrtf((float)(dB0 < 1 ? 1 : dB0));

    #pragma unroll 2
    for (int nt = 0; nt < 16; ++nt) {
        const __hip_bfloat16* w0p = Wt0 + (size_t)(nt * 16 + c) * DDIM + kb * 8;
        s8v wf0[8];
        #pragma unroll
        for (int ks = 0; ks < 8; ++ks) wf0[ks] = *reinterpret_cast<const s8v*>(w0p + ks * 32);
        f4v a00 = (f4v){0.f,0.f,0.f,0.f}, a10 = a00;
        #pragma unroll
        for (int ks = 0; ks < 8; ++ks) {
            a00 = __builtin_amdgcn_mfma_f32_16x16x32_bf16(wf0[ks], xfA[ks], a00, 0, 0, 0);
            a10 = __builtin_amdgcn_mfma_f32_16x16x32_bf16(wf0[ks], xfB[ks], a10, 0, 0, 0);
        }
        const int col = nt * 16 + kb * 4;
        if (vA) {
            uint2 o;
            o.x = pack2(a00[0] * s0A, a00[1] * s0A); o.y = pack2(a00[2] * s0A, a00[3] * s0A);
            *reinterpret_cast<uint2*>(Y0 + (size_t)rA * DDIM + col) = o;
        }
        if (vB) {
            uint2 o;
            o.x = pack2(a10[0] * s0B, a10[1] * s0B); o.y = pack2(a10[2] * s0B, a10[3] * s0B);
            *reinterpret_cast<uint2*>(Y0 + (size_t)rB * DDIM + col) = o;
        }
    }
}

// ---------------- gather helpers (4B records, no per-edge coef) ----------------
__device__ __forceinline__ void addv(f4v& a, uint2 v) {
    a[0] += bf2f(v.x & 0xffffu);
    a[1] += bf2f(v.x >> 16);
    a[2] += bf2f(v.y & 0xffffu);
    a[3] += bf2f(v.y >> 16);
}

__device__ __forceinline__ f4v segsum(const int* __restrict__ srt, int b, int n,
                                      const __hip_bfloat16* __restrict__ Y, int lane) {
    f4v a = (f4v){0.f, 0.f, 0.f, 0.f};
    int j = 0;
    for (; j + 4 <= n; j += 4) {
        const int e0 = __builtin_amdgcn_readfirstlane(srt[b + j + 0]);
        const int e1 = __builtin_amdgcn_readfirstlane(srt[b + j + 1]);
        const int e2 = __builtin_amdgcn_readfirstlane(srt[b + j + 2]);
        const int e3 = __builtin_amdgcn_readfirstlane(srt[b + j + 3]);
        const uint2 v0 = reinterpret_cast<const uint2*>(Y + (size_t)e0 * DDIM)[lane];
        const uint2 v1 = reinterpret_cast<const uint2*>(Y + (size_t)e1 * DDIM)[lane];
        const uint2 v2 = reinterpret_cast<const uint2*>(Y + (size_t)e2 * DDIM)[lane];
        const uint2 v3 = reinterpret_cast<const uint2*>(Y + (size_t)e3 * DDIM)[lane];
        addv(a, v0); addv(a, v1); addv(a, v2); addv(a, v3);
    }
    for (; j < n; ++j) {
        const int e = __builtin_amdgcn_readfirstlane(srt[b + j]);
        addv(a, reinterpret_cast<const uint2*>(Y + (size_t)e * DDIM)[lane]);
    }
    return a;
}

// ---------------- gather (+ optional 2nd relation) + LayerNorm + bias + ReLU ----------------
// starts[] holds segment END after fill_all; beg = end - cnt.
__global__ __launch_bounds__(256) void gather_ln_k(
    const int* __restrict__ srt0, const int* __restrict__ end0, const int* __restrict__ cnt0,
    const __hip_bfloat16* __restrict__ Y0,
    const int* __restrict__ srt1, const int* __restrict__ end1, const int* __restrict__ cnt1,
    const __hip_bfloat16* __restrict__ Y1,
    const float* __restrict__ gamma, const float* __restrict__ beta,
    const float* __restrict__ bias, float* __restrict__ out, int n_dst) {
    const int lane = threadIdx.x & 63, wid = threadIdx.x >> 6;
    const int row = blockIdx.x * 4 + wid;
    if (row >= n_dst) return;

    const int n0 = cnt0[row], e0 = end0[row];
    f4v a = segsum(srt0, e0 - n0, n0, Y0, lane);
    a *= rsqrtf((float)(n0 < 1 ? 1 : n0));
    if (srt1 != nullptr) {
        const int n1 = cnt1[row], e1 = end1[row];
        f4v a1 = segsum(srt1, e1 - n1, n1, Y1, lane);
        a += a1 * rsqrtf((float)(n1 < 1 ? 1 : n1));
    }

    float s1 = a[0] + a[1] + a[2] + a[3];
    float s2 = a[0]*a[0] + a[1]*a[1] + a[2]*a[2] + a[3]*a[3];
    #pragma unroll
    for (int off = 1; off < 64; off <<= 1) {
        s1 += __shfl_xor(s1, off);
        s2 += __shfl_xor(s2, off);
    }
    const float mu = s1 * (1.f / 256.f);
    float var = s2 * (1.f / 256.f) - mu * mu;
    var = fmaxf(var, 0.f);
    const float rs = rsqrtf(var + 1e-5f);

    const f4v g  = reinterpret_cast<const f4v*>(gamma)[lane];
    const f4v be = reinterpret_cast<const f4v*>(beta)[lane];
    const f4v bb = reinterpret_cast<const f4v*>(bias)[lane];
    f4v o;
    #pragma unroll
    for (int j = 0; j < 4; ++j) {
        float v = (a[j] - mu) * rs * g[j] + be[j] + bb[j];
        o[j] = fmaxf(v, 0.f);
    }
    reinterpret_cast<f4v*>(out + (size_t)row * DDIM)[lane] = o;
}

extern "C" void kernel_launch(void* const* d_in, const int* in_sizes, int n_in,
                              void* d_out, int out_size, void* d_ws, size_t ws_size,
                              hipStream_t stream) {
    const float* x_cell     = (const float*)d_in[0];
    const float* x_gene     = (const float*)d_in[1];
    const float* W_cg       = (const float*)d_in[2];
    const float* W_gc       = (const float*)d_in[3];
    const float* W_gg       = (const float*)d_in[4];
    const float* gamma_cell = (const float*)d_in[5];
    const float* beta_cell  = (const float*)d_in[6];
    const float* gamma_gene = (const float*)d_in[7];
    const float* beta_gene  = (const float*)d_in[8];
    const float* b_cell     = (const float*)d_in[9];
    const float* b_gene     = (const float*)d_in[10];
    const int* src_cg = (const int*)d_in[11];
    const int* dst_cg = (const int*)d_in[12];
    const int* src_gc = (const int*)d_in[13];
    const int* dst_gc = (const int*)d_in[14];
    const int* src_gg = (const int*)d_in[15];
    const int* dst_gg = (const int*)d_in[16];

    const int N = in_sizes[0] / DDIM;   // 50000
    const int E = in_sizes[11];         // 800000

    // ---- workspace layout (~37.4 MB) ----
    char* wsb = (char*)d_ws;
    const size_t szN = (size_t)N * 4;            // 200,000
    const size_t szE = (size_t)E * 4;            // 3,200,000
    __hip_bfloat16* Y_gc = (__hip_bfloat16*)wsb;                 // 25.6 MB
    size_t off = (size_t)N * DDIM * 2;
    int* srt_gc = (int*)(wsb + off);  off += szE;
    int* srt_cg = (int*)(wsb + off);  off += szE;
    int* srt_gg = (int*)(wsb + off);  off += szE;
    int* cb     = (int*)(wsb + off);  // 6 count arrays: cs_gc, cd_gc, cs_cg, cd_cg, cs_gg, cd_gg
    const size_t cbOff = off;         off += 6 * szN;
    int* totals = (int*)(wsb + off);  off += 64;
    int* starts = (int*)(wsb + off);  off += 3 * szN;   // start_gc, start_cg, start_gg
    __hip_bfloat16* Wt_gc = (__hip_bfloat16*)(wsb + off); off += (size_t)DDIM * DDIM * 2;
    __hip_bfloat16* Wt_cg = (__hip_bfloat16*)(wsb + off); off += (size_t)DDIM * DDIM * 2;
    __hip_bfloat16* Wt_gg = (__hip_bfloat16*)(wsb + off);

    int* cs_gc = cb;          int* cd_gc = cb + N;
    int* cs_cg = cb + 2 * N;  int* cd_cg = cb + 3 * N;
    int* cs_gg = cb + 4 * N;  int* cd_gg = cb + 5 * N;
    int* start_gc = starts, *start_cg = starts + N, *start_gg = starts + 2 * N;

    // Y_cg, Y_gg live in the d_out cell-half (consumed by gather_gene before
    // gather_cell overwrites that region with the final cell output).
    float* out_cell = (float*)d_out;
    float* out_gene = out_cell + (size_t)N * DDIM;
    __hip_bfloat16* Y_cg = (__hip_bfloat16*)d_out;
    __hip_bfloat16* Y_gg = Y_cg + (size_t)N * DDIM;

    const int cntBlocks = (E + 255) / 256;
    const int nbAlloc   = (N + 255) / 256;
    const int gemmBlocks = (N + 127) / 128;
    const int gatherBlocks = (N + 3) / 4;

    transpose3_k<<<dim3(DDIM, 3), DDIM, 0, stream>>>(W_gc, W_cg, W_gg, Wt_gc, Wt_cg, Wt_gg);
    hipMemsetAsync(wsb + cbOff, 0, 6 * szN + 64, stream);   // counts + totals

    count_all_k<<<cntBlocks, 256, 0, stream>>>(src_gc, dst_gc, src_cg, dst_cg,
                                               src_gg, dst_gg, cb, N, E);
    alloc3_k<<<3 * nbAlloc, 256, 0, stream>>>(cb, starts, totals, N, nbAlloc);
    fill_all_k<<<cntBlocks, 256, 0, stream>>>(src_gc, dst_gc, src_cg, dst_cg,
                                              src_gg, dst_gg, starts,
                                              srt_gc, srt_cg, srt_gg, N, E);

    // x_gene feeds both gc and gg relations: one read, two Y outputs
    gemm2_k<<<gemmBlocks, 256, 0, stream>>>(x_gene, Wt_gc, Wt_gg, cs_gc, cs_gg,
                                            Y_gc, Y_gg, N);
    // x_cell feeds cg
    gemm1_k<<<gemmBlocks, 256, 0, stream>>>(x_cell, Wt_cg, cs_cg, Y_cg, N);

    // gene output first (consumes Y_cg + Y_gg from the cell-half of d_out)
    gather_ln_k<<<gatherBlocks, 256, 0, stream>>>(srt_cg, start_cg, cd_cg, Y_cg,
                                                  srt_gg, start_gg, cd_gg, Y_gg,
                                                  gamma_gene, beta_gene, b_gene, out_gene, N);
    // cell output (consumes Y_gc from ws; overwrites the Y_cg/Y_gg region)
    gather_ln_k<<<gatherBlocks, 256, 0, stream>>>(srt_gc, start_gc, cd_gc, Y_gc,
                                                  nullptr, nullptr, nullptr, nullptr,
                                                  gamma_cell, beta_cell, b_cell, out_cell, N);
}